// Round 4
// baseline (406.472 us; speedup 1.0000x reference)
//
#include <hip/hip_runtime.h>
#include <hip/hip_bf16.h>
#include <stdint.h>

typedef __attribute__((ext_vector_type(8))) short short8;
typedef __attribute__((ext_vector_type(4))) float f32x4;

#define NTILE 31250          // 500000 / 16 rows per n-tile (exact)
#define NCHUNK 7813          // ceil(31250 / 4) 64-row chunks; last chunk = 2 tiles
#define NBLK 256
#define NTHR 512
#define NWAVE_TOT (NBLK * 8)

// LDS map
#define FRAG_OFF   0         // 131072 B : W2 A-fragments (bf16, sigma2-permuted)
#define W1_OFF     131072    // 4096 B   : {W1[0][k],W1[1][k],W1[2][k],b1[k]} fp32
#define SCR_OFF    135168    // 16384 B  : packing scratch (16 W2 rows fp32)
#define LDS_TOTAL  151552

// packed pair convert fp32x2 -> bf16x2 (RNE), lo in [15:0]
__device__ __forceinline__ uint32_t cvtpk(float lo, float hi) {
    uint32_t r;
    asm("v_cvt_pk_bf16_f32 %0, %1, %2" : "=v"(r) : "v"(lo), "v"(hi));
    return r;
}

// hidden-2 permutation: acc slot m' = t*16 + gm*4 + r holds original unit sig2(m').
// Constructed so that layer-3 B-frag position k' = s2*32+g*8+j pulls slot
// (t=2*s2+(j>>2), g, r=j&3) whose unit is exactly k' -> layer-3 uses NATURAL W3.
__device__ __forceinline__ int sig2(int mp) {
    int t = mp >> 4, gm = (mp >> 2) & 3, r = mp & 3;
    return ((t >> 1) << 5) + (gm << 3) + ((t & 1) << 2) + r;
}

__global__ __launch_bounds__(NTHR, 1) void fused_kernel(
    const float* __restrict__ x,  const float* __restrict__ W1,
    const float* __restrict__ b1, const float* __restrict__ W2,
    const float* __restrict__ b2, const float* __restrict__ W3,
    const float* __restrict__ b3, float* __restrict__ out)
{
    extern __shared__ char smem[];
    uint4*  frag4 = (uint4*)(smem + FRAG_OFF);
    float4* w1lds = (float4*)(smem + W1_OFF);
    float*  scrf  = (float*)(smem + SCR_OFF);
    uint4*  scr4  = (uint4*)(smem + SCR_OFF);

    const int tid  = threadIdx.x;
    const int lane = tid & 63;
    const int g    = lane >> 4;   // k-group
    const int lr   = lane & 15;   // row within n-tile / m within A-tile

    // ---- one-time: W1/b1 table into LDS (disjoint region, barrier below covers it)
    if (tid < 256)
        w1lds[tid] = make_float4(W1[tid], W1[256 + tid], W1[512 + tid], b1[tid]);

    // ---- one-time: pack W2 -> A-frags in LDS, 16 passes of 16 rows via scratch ----
    // A-frag(s,t): lane l holds A[m'=t*16+(l&15)][k=s*32+(l>>4)*8+j] = W2[k][sig2(m')]
    const uint4* gw2 = (const uint4*)W2;   // 256x256 fp32 = 16384 uint4
    for (int p = 0; p < 16; ++p) {
        __syncthreads();                       // scratch safe to overwrite
        scr4[tid]       = gw2[p * 1024 + tid];         // rows [16p,16p+16) coalesced
        scr4[tid + 512] = gw2[p * 1024 + 512 + tid];
        __syncthreads();
        int t   = tid >> 5;                    // 0..15
        int l   = (tid & 31) + ((p & 1) << 5); // even p: lanes 0..31 (g=0,1); odd: 32..63
        int c16 = l & 15;
        int s   = p >> 1;
        int c   = sig2(t * 16 + c16);
        int rowbase = ((l >> 4) & 1) * 8;      // local k-row base within the 16 staged rows
        float f[8];
#pragma unroll
        for (int j = 0; j < 8; ++j) f[j] = scrf[(rowbase + j) * 256 + c];
        uint4 wv;
        wv.x = cvtpk(f[0], f[1]); wv.y = cvtpk(f[2], f[3]);
        wv.z = cvtpk(f[4], f[5]); wv.w = cvtpk(f[6], f[7]);
        frag4[(s * 16 + t) * 64 + l] = wv;
    }
    __syncthreads();   // frags + w1lds ready; LDS read-only from here, waves independent

    // ---- per-lane held constants ----
    float4 b2v[16];                       // b2 at this lane's 64 acc slots (sigma2 order)
#pragma unroll
    for (int t = 0; t < 16; ++t) {
        int bc = ((t >> 1) << 5) + (g << 3) + ((t & 1) << 2);   // 16B-aligned
        b2v[t] = *(const float4*)(b2 + bc);
    }
    short8 w3f[8];                        // layer-3 A-frags: A[m=lr][k'=s2*32+g*8+j]=W3[k'][m]
#pragma unroll
    for (int s2 = 0; s2 < 8; ++s2) {
        float f3[8];
#pragma unroll
        for (int j = 0; j < 8; ++j) {
            int kk = s2 * 32 + g * 8 + j;
            f3[j] = (lr < 3) ? W3[kk * 3 + lr] : 0.0f;
        }
        union { short8 s8; uint32_t u[4]; } pw;
        pw.u[0] = cvtpk(f3[0], f3[1]); pw.u[1] = cvtpk(f3[2], f3[3]);
        pw.u[2] = cvtpk(f3[4], f3[5]); pw.u[3] = cvtpk(f3[6], f3[7]);
        w3f[s2] = pw.s8;
    }
    const float b30 = b3[0], b31 = b3[1], b32 = b3[2];

    const short8* afr = (const short8*)(smem + FRAG_OFF);
    const int gwave = blockIdx.x * 8 + (tid >> 6);

    // ---- steady state: 64 batch rows (4 n-tiles) per wave-chunk; VMEM = x + out only
    for (int chunk = gwave; chunk < NCHUNK; chunk += NWAVE_TOT) {
        const int row0 = chunk * 64;

        float q0[4], q1[4], q2[4];
#pragma unroll
        for (int nt = 0; nt < 4; ++nt) {
            if (chunk * 4 + nt < NTILE) {
                const float* xp = x + (size_t)(row0 + nt * 16 + lr) * 9;
                float a0 = xp[0], a1 = xp[1], a2 = xp[2], a3 = xp[3], a4 = xp[4];
                float a5 = xp[5], a6 = xp[6], a7 = xp[7], a8 = xp[8];
                float d0 = a0 - a3, d1 = a1 - a4, d2 = a2 - a5;
                float e0 = a0 - a6, e1 = a1 - a7, e2 = a2 - a8;
                float f0 = a3 - a6, f1 = a4 - a7, f2 = a5 - a8;
                q0[nt] = sqrtf(fmaf(d0, d0, fmaf(d1, d1, d2 * d2)));
                q1[nt] = sqrtf(fmaf(e0, e0, fmaf(e1, e1, e2 * e2)));
                q2[nt] = sqrtf(fmaf(f0, f0, fmaf(f1, f1, f2 * f2)));
            } else { q0[nt] = 1.f; q1[nt] = 1.f; q2[nt] = 1.f; }
        }

        // acc init = b2 (fold the layer-2 bias)
        f32x4 acc[16][4];
#pragma unroll
        for (int t = 0; t < 16; ++t) {
            f32x4 bi; bi[0] = b2v[t].x; bi[1] = b2v[t].y; bi[2] = b2v[t].z; bi[3] = b2v[t].w;
#pragma unroll
            for (int nt = 0; nt < 4; ++nt) acc[t][nt] = bi;
        }

        // K loop: layer-1 on VALU -> bf16 B-frags; A = permuted W2 frags from LDS
#pragma unroll 1
        for (int s = 0; s < 8; ++s) {
            float4 wv[8];
#pragma unroll
            for (int j = 0; j < 8; ++j) wv[j] = w1lds[s * 32 + g * 8 + j];
            short8 hb[4];
#pragma unroll
            for (int nt = 0; nt < 4; ++nt) {
                union { short8 s8; uint32_t u[4]; } pk;
#pragma unroll
                for (int jj = 0; jj < 4; ++jj) {
                    float4 wa = wv[2 * jj], wb = wv[2 * jj + 1];
                    float ha = fmaf(q0[nt], wa.x, fmaf(q1[nt], wa.y, fmaf(q2[nt], wa.z, wa.w)));
                    float hc = fmaf(q0[nt], wb.x, fmaf(q1[nt], wb.y, fmaf(q2[nt], wb.z, wb.w)));
                    pk.u[jj] = cvtpk(fmaxf(ha, 0.f), fmaxf(hc, 0.f));
                }
                hb[nt] = pk.s8;
            }
#pragma unroll
            for (int t = 0; t < 16; ++t) {
                short8 av = afr[(s * 16 + t) * 64 + lane];
#pragma unroll
                for (int nt = 0; nt < 4; ++nt)
                    acc[t][nt] = __builtin_amdgcn_mfma_f32_16x16x32_bf16(av, hb[nt], acc[t][nt], 0, 0, 0);
            }
        }

        // layer 3 via MFMA (lane-local slot->k' mapping), then eigen + store
#pragma unroll
        for (int nt = 0; nt < 4; ++nt) {
            f32x4 D = {0.f, 0.f, 0.f, 0.f};
#pragma unroll
            for (int s2 = 0; s2 < 8; ++s2) {
                union { short8 s8; uint32_t u[4]; } pb;
                pb.u[0] = cvtpk(fmaxf(acc[2 * s2][nt][0], 0.f), fmaxf(acc[2 * s2][nt][1], 0.f));
                pb.u[1] = cvtpk(fmaxf(acc[2 * s2][nt][2], 0.f), fmaxf(acc[2 * s2][nt][3], 0.f));
                pb.u[2] = cvtpk(fmaxf(acc[2 * s2 + 1][nt][0], 0.f), fmaxf(acc[2 * s2 + 1][nt][1], 0.f));
                pb.u[3] = cvtpk(fmaxf(acc[2 * s2 + 1][nt][2], 0.f), fmaxf(acc[2 * s2 + 1][nt][3], 0.f));
                D = __builtin_amdgcn_mfma_f32_16x16x32_bf16(w3f[s2], pb.s8, D, 0, 0, 0);
            }
            // D layout: col=lane&15 = batch row, row m = g*4+reg; g==0 holds m=0..2
            if (g == 0 && (chunk * 4 + nt) < NTILE) {
                float w0 = D[0] + b30, w1v = D[1] + b31, wc = D[2] + b32;
                float mm = 0.5f * (w0 + w1v), dd = 0.5f * (w0 - w1v);
                float rad = sqrtf(fmaf(dd, dd, wc * wc));
                int row = row0 + nt * 16 + lr;
                *(float2*)(out + (size_t)row * 2) = make_float2(mm - rad, mm + rad);
            }
        }
    }
}

extern "C" void kernel_launch(void* const* d_in, const int* in_sizes, int n_in,
                              void* d_out, int out_size, void* d_ws, size_t ws_size,
                              hipStream_t stream) {
    const float* x  = (const float*)d_in[0];
    const float* W1 = (const float*)d_in[1];
    const float* b1 = (const float*)d_in[2];
    const float* W2 = (const float*)d_in[3];
    const float* b2 = (const float*)d_in[4];
    const float* W3 = (const float*)d_in[5];
    const float* b3 = (const float*)d_in[6];
    float* out = (float*)d_out;

    (void)d_ws; (void)ws_size;

    // allow 148 KB dynamic LDS (not a stream op; capture-safe)
    (void)hipFuncSetAttribute((const void*)fused_kernel,
                              hipFuncAttributeMaxDynamicSharedMemorySize, LDS_TOTAL);

    fused_kernel<<<NBLK, NTHR, LDS_TOTAL, stream>>>(x, W1, b1, W2, b2, W3, b3, out);
}

// Round 5
// 159.051 us; speedup vs baseline: 2.5556x; 2.5556x over previous
//
#include <hip/hip_runtime.h>
#include <hip/hip_bf16.h>
#include <stdint.h>

typedef __attribute__((ext_vector_type(8))) short short8;
typedef __attribute__((ext_vector_type(4))) float f32x4;

#define NCHUNK 15625         // 500000 / 32 rows per chunk (exact)
#define NBLK 256
#define NTHR 512
#define NWAVE_TOT (NBLK * 8)

// LDS map
#define FRAG_OFF   0         // 131072 B : W2 A-fragments (bf16, sigma2-permuted)
#define W1_OFF     131072    // 4096 B   : {W1[0][k],W1[1][k],W1[2][k],b1[k]} fp32
#define B2_OFF     135168    // 1024 B   : b2 raw fp32
#define SCR_OFF    136192    // 16384 B  : packing scratch (16 W2 rows fp32)
#define LDS_TOTAL  152576

// packed pair convert fp32x2 -> bf16x2 (RNE), lo in [15:0]
__device__ __forceinline__ uint32_t cvtpk(float lo, float hi) {
    uint32_t r;
    asm("v_cvt_pk_bf16_f32 %0, %1, %2" : "=v"(r) : "v"(lo), "v"(hi));
    return r;
}

// hidden-2 permutation: acc slot m' = t*16 + gm*4 + r holds original unit sig2(m').
// sig2(t,gm,r) = ((t>>1)<<5) + (gm<<3) + ((t&1)<<2) + r, so layer-3 B-frag position
// k' = s2*32 + g*8 + j pulls slot (t = 2*s2 + (j>>2), g, r = j&3) whose unit is
// exactly k' -> layer-3 uses NATURAL-order W3 fragments. (HW-verified, r4 absmax.)
__device__ __forceinline__ int sig2(int mp) {
    int t = mp >> 4, gm = (mp >> 2) & 3, r = mp & 3;
    return ((t >> 1) << 5) + (gm << 3) + ((t & 1) << 2) + r;
}

__global__ __launch_bounds__(NTHR, 2) void fused_kernel(
    const float* __restrict__ x,  const float* __restrict__ W1,
    const float* __restrict__ b1, const float* __restrict__ W2,
    const float* __restrict__ b2, const float* __restrict__ W3,
    const float* __restrict__ b3, float* __restrict__ out)
{
    extern __shared__ char smem[];
    uint4*  frag4 = (uint4*)(smem + FRAG_OFF);
    float4* w1lds = (float4*)(smem + W1_OFF);
    float4* b2lds = (float4*)(smem + B2_OFF);
    float*  scrf  = (float*)(smem + SCR_OFF);
    uint4*  scr4  = (uint4*)(smem + SCR_OFF);

    const int tid  = threadIdx.x;
    const int lane = tid & 63;
    const int g    = lane >> 4;   // k-group
    const int lr   = lane & 15;   // batch row within 16-row tile / m within A-tile

    // ---- one-time: W1/b1 table + b2 into LDS (disjoint regions) ----
    if (tid < 256)
        w1lds[tid] = make_float4(W1[tid], W1[256 + tid], W1[512 + tid], b1[tid]);
    else if (tid < 320)
        b2lds[tid - 256] = ((const float4*)b2)[tid - 256];

    // ---- one-time: pack W2 -> A-frags in LDS (16 passes of 16 rows via scratch) ----
    // A-frag(s,t): lane l holds A[m'=t*16+(l&15)][k=s*32+(l>>4)*8+j] = W2[k][sig2(m')]
    const uint4* gw2 = (const uint4*)W2;   // 256x256 fp32 = 16384 uint4
    for (int p = 0; p < 16; ++p) {
        __syncthreads();                       // scratch safe to overwrite
        scr4[tid]       = gw2[p * 1024 + tid];         // rows [16p,16p+16) coalesced
        scr4[tid + 512] = gw2[p * 1024 + 512 + tid];
        __syncthreads();
        int t   = tid >> 5;                    // 0..15
        int l   = (tid & 31) + ((p & 1) << 5); // even p: lanes 0..31; odd: 32..63
        int c16 = l & 15;
        int s   = p >> 1;
        int c   = sig2(t * 16 + c16);
        int rowbase = ((l >> 4) & 1) * 8;      // local k-row base within staged 16 rows
        float f[8];
#pragma unroll
        for (int j = 0; j < 8; ++j) f[j] = scrf[(rowbase + j) * 256 + c];
        uint4 wv;
        wv.x = cvtpk(f[0], f[1]); wv.y = cvtpk(f[2], f[3]);
        wv.z = cvtpk(f[4], f[5]); wv.w = cvtpk(f[6], f[7]);
        frag4[(s * 16 + t) * 64 + l] = wv;
    }
    __syncthreads();   // LDS read-only from here; waves fully independent

    // ---- per-lane held constants: layer-3 A-frags (32 VGPRs) ----
    short8 w3f[8];     // A[m=lr][k'=s2*32+g*8+j] = W3[k'][m] (m<3 else 0)
#pragma unroll
    for (int s2 = 0; s2 < 8; ++s2) {
        float f3[8];
#pragma unroll
        for (int j = 0; j < 8; ++j) {
            int kk = s2 * 32 + g * 8 + j;
            f3[j] = (lr < 3) ? W3[kk * 3 + lr] : 0.0f;
        }
        union { short8 s8; uint32_t u[4]; } pw;
        pw.u[0] = cvtpk(f3[0], f3[1]); pw.u[1] = cvtpk(f3[2], f3[3]);
        pw.u[2] = cvtpk(f3[4], f3[5]); pw.u[3] = cvtpk(f3[6], f3[7]);
        w3f[s2] = pw.s8;
    }
    const float b30 = b3[0], b31 = b3[1], b32 = b3[2];

    const short8* afr = (const short8*)(smem + FRAG_OFF);
    const int gwave = blockIdx.x * 8 + (tid >> 6);

    // ---- steady state: 32 batch rows per wave-chunk; VMEM = x loads + out store only
    for (int chunk = gwave; chunk < NCHUNK; chunk += NWAVE_TOT) {
        const int row0 = chunk * 32;

        float q0[2], q1[2], q2[2];
#pragma unroll
        for (int nt = 0; nt < 2; ++nt) {
            const float* xp = x + (size_t)(row0 + nt * 16 + lr) * 9;
            float a0 = xp[0], a1 = xp[1], a2 = xp[2], a3 = xp[3], a4 = xp[4];
            float a5 = xp[5], a6 = xp[6], a7 = xp[7], a8 = xp[8];
            float d0 = a0 - a3, d1 = a1 - a4, d2 = a2 - a5;
            float e0 = a0 - a6, e1 = a1 - a7, e2 = a2 - a8;
            float f0 = a3 - a6, f1 = a4 - a7, f2 = a5 - a8;
            q0[nt] = sqrtf(fmaf(d0, d0, fmaf(d1, d1, d2 * d2)));
            q1[nt] = sqrtf(fmaf(e0, e0, fmaf(e1, e1, e2 * e2)));
            q2[nt] = sqrtf(fmaf(f0, f0, fmaf(f1, f1, f2 * f2)));
        }

        // acc init = b2 at this lane's sigma2 slots (16 broadcast ds_read_b128)
        f32x4 acc[16][2];
#pragma unroll
        for (int t = 0; t < 16; ++t) {
            int bc4 = (((t >> 1) << 5) + (g << 3) + ((t & 1) << 2)) >> 2;
            float4 bv = b2lds[bc4];
            f32x4 bi; bi[0] = bv.x; bi[1] = bv.y; bi[2] = bv.z; bi[3] = bv.w;
            acc[t][0] = bi; acc[t][1] = bi;
        }

        // K loop: layer-1 on VALU -> bf16 B-frags; A = permuted W2 frags from LDS
#pragma unroll 1
        for (int s = 0; s < 8; ++s) {
            float4 wv[8];
#pragma unroll
            for (int j = 0; j < 8; ++j) wv[j] = w1lds[s * 32 + g * 8 + j];
            short8 hb[2];
#pragma unroll
            for (int nt = 0; nt < 2; ++nt) {
                union { short8 s8; uint32_t u[4]; } pk;
#pragma unroll
                for (int jj = 0; jj < 4; ++jj) {
                    float4 wa = wv[2 * jj], wb = wv[2 * jj + 1];
                    float ha = fmaf(q0[nt], wa.x, fmaf(q1[nt], wa.y, fmaf(q2[nt], wa.z, wa.w)));
                    float hc = fmaf(q0[nt], wb.x, fmaf(q1[nt], wb.y, fmaf(q2[nt], wb.z, wb.w)));
                    pk.u[jj] = cvtpk(fmaxf(ha, 0.f), fmaxf(hc, 0.f));
                }
                hb[nt] = pk.s8;
            }
#pragma unroll
            for (int t = 0; t < 16; ++t) {
                short8 av = afr[(s * 16 + t) * 64 + lane];
                acc[t][0] = __builtin_amdgcn_mfma_f32_16x16x32_bf16(av, hb[0], acc[t][0], 0, 0, 0);
                acc[t][1] = __builtin_amdgcn_mfma_f32_16x16x32_bf16(av, hb[1], acc[t][1], 0, 0, 0);
            }
        }

        // layer 3 via MFMA (lane-local slot->k' mapping), then eigen + store
#pragma unroll
        for (int nt = 0; nt < 2; ++nt) {
            f32x4 D = {0.f, 0.f, 0.f, 0.f};
#pragma unroll
            for (int s2 = 0; s2 < 8; ++s2) {
                union { short8 s8; uint32_t u[4]; } pb;
                pb.u[0] = cvtpk(fmaxf(acc[2 * s2][nt][0], 0.f), fmaxf(acc[2 * s2][nt][1], 0.f));
                pb.u[1] = cvtpk(fmaxf(acc[2 * s2][nt][2], 0.f), fmaxf(acc[2 * s2][nt][3], 0.f));
                pb.u[2] = cvtpk(fmaxf(acc[2 * s2 + 1][nt][0], 0.f), fmaxf(acc[2 * s2 + 1][nt][1], 0.f));
                pb.u[3] = cvtpk(fmaxf(acc[2 * s2 + 1][nt][2], 0.f), fmaxf(acc[2 * s2 + 1][nt][3], 0.f));
                D = __builtin_amdgcn_mfma_f32_16x16x32_bf16(w3f[s2], pb.s8, D, 0, 0, 0);
            }
            // D: lane holds D[m = g*4 + reg][batch col = lr]; g==0 has m=0..2
            if (g == 0) {
                float w0 = D[0] + b30, w1v = D[1] + b31, wc = D[2] + b32;
                float mm = 0.5f * (w0 + w1v), dd = 0.5f * (w0 - w1v);
                float rad = sqrtf(fmaf(dd, dd, wc * wc));
                int row = row0 + nt * 16 + lr;
                *(float2*)(out + (size_t)row * 2) = make_float2(mm - rad, mm + rad);
            }
        }
    }
}

extern "C" void kernel_launch(void* const* d_in, const int* in_sizes, int n_in,
                              void* d_out, int out_size, void* d_ws, size_t ws_size,
                              hipStream_t stream) {
    const float* x  = (const float*)d_in[0];
    const float* W1 = (const float*)d_in[1];
    const float* b1 = (const float*)d_in[2];
    const float* W2 = (const float*)d_in[3];
    const float* b2 = (const float*)d_in[4];
    const float* W3 = (const float*)d_in[5];
    const float* b3 = (const float*)d_in[6];
    float* out = (float*)d_out;

    (void)d_ws; (void)ws_size;

    // allow 149 KB dynamic LDS (not a stream op; capture-safe)
    (void)hipFuncSetAttribute((const void*)fused_kernel,
                              hipFuncAttributeMaxDynamicSharedMemorySize, LDS_TOTAL);

    fused_kernel<<<NBLK, NTHR, LDS_TOTAL, stream>>>(x, W1, b1, W2, b2, W3, b3, out);
}

// Round 6
// 145.018 us; speedup vs baseline: 2.8029x; 1.0968x over previous
//
#include <hip/hip_runtime.h>
#include <hip/hip_bf16.h>
#include <stdint.h>

typedef __attribute__((ext_vector_type(8)))  short short8;
typedef __attribute__((ext_vector_type(16))) float f32x16;

#define NCHUNK 15625         // 500000 / 32 rows per chunk (exact, no tail)
#define NBLK 256
#define NTHR 512
#define NWAVE_TOT (NBLK * 8)

// swap bits 2<->3 (involution); the single permutation that aligns MFMA D-layout
// (row = (reg&3) + 8*(reg>>2) + 4*hi) with B-frag k-layout (k = 16kt + 8hi + j)
#define SW(v) ((((v) & ~12u)) | (((v) & 4u) << 1) | (((v) & 8u) >> 1))

// LDS map (bytes)
#define A2_OFF   0           // 131072 : W2 A-frags, frag(kt,mt) @ (kt*8+mt)*1024 + l*16
#define A1_OFF   131072      // 4096   : [W1t|b1] A-frags, lo lanes only: fr*512 + c*16
#define Z_OFF    135168      // 16     : shared zero block (broadcast reads)
#define A3_OFF   135184      // 1536   : W3 A-frags: kt*96 + (hi*3+c)*16 (c<3)
#define SCR_OFF  136720      // 16384  : packing scratch (16 W2 rows fp32)
#define LDS_TOTAL 153104

__device__ __forceinline__ uint32_t cvtpk(float lo, float hi) {
    uint32_t r;
    asm("v_cvt_pk_bf16_f32 %0, %1, %2" : "=v"(r) : "v"(lo), "v"(hi));
    return r;
}

__global__ __launch_bounds__(NTHR, 2) void fused_kernel(
    const float* __restrict__ x,  const float* __restrict__ W1,
    const float* __restrict__ b1, const float* __restrict__ W2,
    const float* __restrict__ b2, const float* __restrict__ W3,
    const float* __restrict__ b3, float* __restrict__ out)
{
    extern __shared__ char smem[];
    uint4* frag4 = (uint4*)(smem + A2_OFF);
    float* scrf  = (float*)(smem + SCR_OFF);
    uint4* scr4  = (uint4*)(smem + SCR_OFF);

    const int tid = threadIdx.x;
    const int l   = tid & 63;
    const int hi  = l >> 5;       // k-half within frags
    const int c   = l & 31;       // batch column / A-row within tile

    // ================= one-time packing =================
    // Phase A: layer-1 A-frags: A1[row = fr*32+c][k] = {W1[0][r],W1[1][r],W1[2][r],b1[r],0..}
    {
        int fr = tid >> 6, l2 = tid & 63;
        if (l2 < 32) {
            int row = fr * 32 + l2;
            uint4 v;
            v.x = cvtpk(W1[row], W1[256 + row]);
            v.y = cvtpk(W1[512 + row], b1[row]);
            v.z = 0; v.w = 0;
            ((uint4*)(smem + A1_OFF))[fr * 32 + l2] = v;
        }
        if (tid == 511) ((uint4*)(smem + Z_OFF))[0] = make_uint4(0, 0, 0, 0);
        // Phase B: layer-3 A-frags: A3[row=c2][k'=16fr+8hi2+j] = W3[k'][c2], c2<3
        if (tid < 96) {
            int fr3 = tid / 6, rem = tid % 6, hi2 = rem / 3, c2 = rem % 3;
            int kb = 16 * fr3 + 8 * hi2;
            uint4 v;
            v.x = cvtpk(W3[(kb + 0) * 3 + c2], W3[(kb + 1) * 3 + c2]);
            v.y = cvtpk(W3[(kb + 2) * 3 + c2], W3[(kb + 3) * 3 + c2]);
            v.z = cvtpk(W3[(kb + 4) * 3 + c2], W3[(kb + 5) * 3 + c2]);
            v.w = cvtpk(W3[(kb + 6) * 3 + c2], W3[(kb + 7) * 3 + c2]);
            ((uint4*)(smem + A3_OFF))[fr3 * 6 + rem] = v;
        }
    }
    // Phase C: W2 -> A2-frags: elem j of frag(kt,mt) at lane (hi,c):
    //   W2[SW(16kt+8hi+j)][SW(32mt+c)]  (16 passes, 16 rows staged per pass)
    const uint4* gw2 = (const uint4*)W2;
    for (int kt = 0; kt < 16; ++kt) {
        __syncthreads();
        scr4[tid]       = gw2[kt * 1024 + tid];
        scr4[tid + 512] = gw2[kt * 1024 + 512 + tid];
        __syncthreads();
        int mt = tid >> 6, l2 = tid & 63, hi2 = l2 >> 5, c2 = l2 & 31;
        int col = 32 * mt + (int)SW((unsigned)c2);
        float f[8];
#pragma unroll
        for (int j = 0; j < 8; ++j) {
            int lrow = 8 * (j >> 2) + 4 * hi2 + (j & 3);   // SW(16kt+8hi2+j) - 16kt
            f[j] = scrf[lrow * 256 + col];
        }
        uint4 v;
        v.x = cvtpk(f[0], f[1]); v.y = cvtpk(f[2], f[3]);
        v.z = cvtpk(f[4], f[5]); v.w = cvtpk(f[6], f[7]);
        frag4[(kt * 8 + mt) * 64 + l2] = v;
    }
    __syncthreads();   // LDS read-only from here; waves fully independent

    // ================= per-lane held constants =================
    const f32x16 Z = {0,0,0,0,0,0,0,0,0,0,0,0,0,0,0,0};
    uint32_t b2pk[8];                 // bf16(b2[SW(32mt+c)]) in low 16, lo lanes only
#pragma unroll
    for (int mt = 0; mt < 8; ++mt)
        b2pk[mt] = hi ? 0u : cvtpk(b2[32 * mt + (int)SW((unsigned)c)], 0.0f);
    union { short8 s8; uint32_t u[4]; } bB;   // bias B-frag: B[0][*]=1 (lo lanes)
    bB.u[0] = hi ? 0u : 0x3F80u; bB.u[1] = 0; bB.u[2] = 0; bB.u[3] = 0;
    const short8 biasB = bB.s8;
    const float b30 = b3[0], b31 = b3[1], b32 = b3[2];

    const int a1step = hi ? 0 : 512;
    const int a1base = hi ? Z_OFF : (A1_OFF + c * 16);
    const int a3step = (c < 3) ? 96 : 0;
    const int a3base = (c < 3) ? (A3_OFF + (hi * 3 + c) * 16) : Z_OFF;

    const int gwave = blockIdx.x * 8 + (tid >> 6);

    // preload x for first chunk (lane's batch row = chunk*32 + c; both halves dup)
    float xb[9], xn[9];
    {
        const float* xp = x + (size_t)(gwave * 32 + c) * 9;
#pragma unroll
        for (int j = 0; j < 9; ++j) xb[j] = xp[j];
    }

    // ================= steady state =================
    for (int chunk = gwave; chunk < NCHUNK; chunk += NWAVE_TOT) {
        // prefetch next chunk's x (reload current if none) — hides HBM latency
        {
            int nxt = chunk + NWAVE_TOT;
            const float* xpn = x + (size_t)(((nxt < NCHUNK) ? nxt : chunk) * 32 + c) * 9;
#pragma unroll
            for (int j = 0; j < 9; ++j) xn[j] = xpn[j];
        }
        // bond lengths (fp32)
        float d0 = xb[0] - xb[3], d1 = xb[1] - xb[4], d2 = xb[2] - xb[5];
        float e0 = xb[0] - xb[6], e1 = xb[1] - xb[7], e2 = xb[2] - xb[8];
        float f0 = xb[3] - xb[6], f1 = xb[4] - xb[7], f2 = xb[5] - xb[8];
        float q0 = sqrtf(fmaf(d0, d0, fmaf(d1, d1, d2 * d2)));
        float q1 = sqrtf(fmaf(e0, e0, fmaf(e1, e1, e2 * e2)));
        float q2 = sqrtf(fmaf(f0, f0, fmaf(f1, f1, f2 * f2)));

        // layer-1 B-frag: B[k][col=c] = {q0,q1,q2,1,0...} on lo lanes
        union { short8 s8; uint32_t u[4]; } qf;
        qf.u[0] = hi ? 0u : cvtpk(q0, q1);
        qf.u[1] = hi ? 0u : cvtpk(q2, 1.0f);
        qf.u[2] = 0; qf.u[3] = 0;
        const short8 qfrag = qf.s8;

        // acc init = b2 via bias-MFMA (D[row][col] = b2[SW(32mt+row)])
        f32x16 acc[8];
#pragma unroll
        for (int mt = 0; mt < 8; ++mt) {
            union { short8 s8; uint32_t u[4]; } bA;
            bA.u[0] = b2pk[mt]; bA.u[1] = 0; bA.u[2] = 0; bA.u[3] = 0;
            acc[mt] = __builtin_amdgcn_mfma_f32_32x32x16_bf16(bA.s8, biasB, Z, 0, 0, 0);
        }

        // layer-1 tile -> pack -> layer-2, one 32-unit h1-tile at a time
#pragma unroll
        for (int tau = 0; tau < 8; ++tau) {
            short8 a1 = *(const short8*)(smem + a1base + tau * a1step);
            f32x16 d1v = __builtin_amdgcn_mfma_f32_32x32x16_bf16(a1, qfrag, Z, 0, 0, 0);
#pragma unroll
            for (int p = 0; p < 2; ++p) {
                const int kt = 2 * tau + p;
                union { short8 s8; uint32_t u[4]; } pk;
#pragma unroll
                for (int w = 0; w < 4; ++w)
                    pk.u[w] = cvtpk(fmaxf(d1v[8 * p + 2 * w], 0.0f),
                                    fmaxf(d1v[8 * p + 2 * w + 1], 0.0f));
                const short8 bfr = pk.s8;
#pragma unroll
                for (int mt = 0; mt < 8; ++mt) {
                    short8 a2 = *(const short8*)(smem + (size_t)(kt * 8 + mt) * 1024 + l * 16);
                    acc[mt] = __builtin_amdgcn_mfma_f32_32x32x16_bf16(a2, bfr, acc[mt], 0, 0, 0);
                }
            }
        }

        // layer-3: 16 MFMAs; B3-frag for kt' = relu(acc[kt'>>1] regs 8*(kt'&1)..+7)
        f32x16 d3 = Z;
#pragma unroll
        for (int kt3 = 0; kt3 < 16; ++kt3) {
            const int mt = kt3 >> 1, p = kt3 & 1;
            union { short8 s8; uint32_t u[4]; } pk;
#pragma unroll
            for (int w = 0; w < 4; ++w)
                pk.u[w] = cvtpk(fmaxf(acc[mt][8 * p + 2 * w], 0.0f),
                                fmaxf(acc[mt][8 * p + 2 * w + 1], 0.0f));
            short8 a3 = *(const short8*)(smem + a3base + kt3 * a3step);
            d3 = __builtin_amdgcn_mfma_f32_32x32x16_bf16(a3, pk.s8, d3, 0, 0, 0);
        }

        // eigen + store: lo lanes hold d3 regs 0,1,2 = (w00,w11,w01) for batch col c
        if (hi == 0) {
            float w0 = d3[0] + b30, w1v = d3[1] + b31, wc = d3[2] + b32;
            float mm = 0.5f * (w0 + w1v), dd = 0.5f * (w0 - w1v);
            float rad = sqrtf(fmaf(dd, dd, wc * wc));
            *(float2*)(out + (size_t)(chunk * 32 + c) * 2) = make_float2(mm - rad, mm + rad);
        }

        // rotate prefetched x
#pragma unroll
        for (int j = 0; j < 9; ++j) xb[j] = xn[j];
    }
}

extern "C" void kernel_launch(void* const* d_in, const int* in_sizes, int n_in,
                              void* d_out, int out_size, void* d_ws, size_t ws_size,
                              hipStream_t stream) {
    const float* x  = (const float*)d_in[0];
    const float* W1 = (const float*)d_in[1];
    const float* b1 = (const float*)d_in[2];
    const float* W2 = (const float*)d_in[3];
    const float* b2 = (const float*)d_in[4];
    const float* W3 = (const float*)d_in[5];
    const float* b3 = (const float*)d_in[6];
    float* out = (float*)d_out;

    (void)d_ws; (void)ws_size;

    (void)hipFuncSetAttribute((const void*)fused_kernel,
                              hipFuncAttributeMaxDynamicSharedMemorySize, LDS_TOTAL);

    fused_kernel<<<NBLK, NTHR, LDS_TOTAL, stream>>>(x, W1, b1, W2, b2, W3, b3, out);
}